// Round 3
// baseline (233.286 us; speedup 1.0000x reference)
//
#include <hip/hip_runtime.h>

#define BUFSZ 10000000LL
#define RESF 0.3f

// XLA canonicalizes x / const -> x * (1/const); 1.0f/0.3f constant-folds to
// the correctly-rounded f32 0x40555555 = 3.33333325386047363281f.
#define RINV (1.0f / 0.3f)

// ---------------------------------------------------------------------------
// Pass A: per-point grid via reciprocal-mul (XLA semantics) + f32 distance to
// voxel center, atomicMin on f32 bit pattern (exact segment-min for d >= 0).
// ---------------------------------------------------------------------------
__global__ __launch_bounds__(256) void pass_min(
    const float* __restrict__ points,
    unsigned int* __restrict__ seg,
    int N)
{
#pragma clang fp contract(off)
    int i = blockIdx.x * 256 + threadIdx.x;
    if (i >= N) return;

    float px = points[3 * i + 0];
    float py = points[3 * i + 1];
    float pz = points[3 * i + 2];

    float fx = floorf(px * RINV);
    float fy = floorf(py * RINV);
    float fz = floorf(pz * RINV);

    long long gx = (long long)fx;
    long long gy = (long long)fy;
    long long gz = (long long)fz;
    long long s = gx * 73856093LL + gy * 19349669LL + gz * 83492791LL;
    long long h = s % BUFSZ;                      // trunc, sign of dividend
    int hw = (int)(h < 0 ? h + BUFSZ : h);

    float cx = (fx + 0.5f) * RESF;
    float cy = (fy + 0.5f) * RESF;
    float cz = (fz + 0.5f) * RESF;
    float dx = px - cx;
    float dy = py - cy;
    float dz = pz - cz;
    float d = dx * dx + dy * dy + dz * dz;        // ((xx+yy)+zz), no contraction

    atomicMin(seg + hw, __float_as_uint(d));
}

// ---------------------------------------------------------------------------
// Pass B: recompute grid + d_center identically (same rounding), compare to
// bucket min, gather, emit the three outputs.
// ---------------------------------------------------------------------------
__global__ __launch_bounds__(256) void pass_out(
    const float* __restrict__ points,
    const float* __restrict__ neural,
    const int* __restrict__ bufidx,
    const float* __restrict__ travel,
    const int* __restrict__ ts_upd,
    const int* __restrict__ cur_ts_p,
    const unsigned int* __restrict__ seg,
    float* __restrict__ out,
    int N, int M)
{
#pragma clang fp contract(off)
    int i = blockIdx.x * 256 + threadIdx.x;
    if (i >= N) return;

    float px = points[3 * i + 0];
    float py = points[3 * i + 1];
    float pz = points[3 * i + 2];

    float fx = floorf(px * RINV);
    float fy = floorf(py * RINV);
    float fz = floorf(pz * RINV);

    long long gx = (long long)fx;
    long long gy = (long long)fy;
    long long gz = (long long)fz;
    long long s = gx * 73856093LL + gy * 19349669LL + gz * 83492791LL;
    long long h = s % BUFSZ;
    int hw = (int)(h < 0 ? h + BUFSZ : h);

    float cx = (fx + 0.5f) * RESF;
    float cy = (fy + 0.5f) * RESF;
    float cz = (fz + 0.5f) * RESF;
    float dx = px - cx;
    float dy = py - cy;
    float dz = pz - cz;
    float d = dx * dx + dy * dy + dz * dz;

    bool keep = __float_as_uint(d) <= seg[hw];

    int hidx = bufidx[hw];                        // -1 == empty slot
    int idxw = (hidx < 0) ? (hidx + M) : hidx;    // negative wrap -> M-1

    float vx = neural[3 * idxw + 0] - px;
    float vy = neural[3 * idxw + 1] - py;
    float vz = neural[3 * idxw + 2] - pz;
    float dist2 = vx * vx + vy * vy + vz * vz;    // no contraction

    int ts = ts_upd[idxw];
    float dtv = travel[cur_ts_p[0]] - travel[ts];

    const float THR = (float)(3.0 * 0.3 * 0.3);   // Python double -> f32
    bool upd = keep && ((hidx == -1) || (dist2 > THR) || (dtv > 120.0f));

    out[i]         = dist2;
    out[N + i]     = dtv;
    out[2 * N + i] = upd ? 1.0f : 0.0f;
}

extern "C" void kernel_launch(void* const* d_in, const int* in_sizes, int n_in,
                              void* d_out, int out_size, void* d_ws, size_t ws_size,
                              hipStream_t stream)
{
    const float* points  = (const float*)d_in[0];
    const float* neural  = (const float*)d_in[1];
    const int*   bufidx  = (const int*)d_in[2];
    const float* travel  = (const float*)d_in[3];
    const int*   ts_upd  = (const int*)d_in[4];
    const int*   cur_ts  = (const int*)d_in[5];

    int N = in_sizes[0] / 3;
    int M = in_sizes[1] / 3;

    unsigned int* seg = (unsigned int*)d_ws;      // 10M * 4 = 40 MB scratch

    hipMemsetAsync(seg, 0xFF, (size_t)BUFSZ * sizeof(unsigned int), stream);

    int blocks = (N + 255) / 256;
    pass_min<<<blocks, 256, 0, stream>>>(points, seg, N);
    pass_out<<<blocks, 256, 0, stream>>>(points, neural, bufidx, travel, ts_upd,
                                         cur_ts, seg, (float*)d_out, N, M);
}

// Round 4
// 186.877 us; speedup vs baseline: 1.2483x; 1.2483x over previous
//
#include <hip/hip_runtime.h>

#define BUFSZ 10000000
#define RESF 0.3f
// XLA canonicalizes x / const -> x * (1/const); 1.0f/0.3f folds to 0x40555555.
#define RINV (1.0f / 0.3f)

// ---------------------------------------------------------------------------
// Shared per-point voxel math — MUST stay bit-identical across passes and to
// the R3-passing kernel (recip-mul grid, (f+0.5)*0.3 center, ((xx+yy)+zz)).
// ---------------------------------------------------------------------------
__device__ __forceinline__ void voxel_hash_d(float px, float py, float pz,
                                             int& hw, unsigned& dbits)
{
#pragma clang fp contract(off)
    float fx = floorf(px * RINV);
    float fy = floorf(py * RINV);
    float fz = floorf(pz * RINV);

    long long gx = (long long)fx;
    long long gy = (long long)fy;
    long long gz = (long long)fz;
    long long s = gx * 73856093LL + gy * 19349669LL + gz * 83492791LL;
    long long h = s % (long long)BUFSZ;           // trunc, sign of dividend
    hw = (int)(h < 0 ? h + BUFSZ : h);

    float cx = (fx + 0.5f) * RESF;
    float cy = (fy + 0.5f) * RESF;
    float cz = (fz + 0.5f) * RESF;
    float dx = px - cx;
    float dy = py - cy;
    float dz = pz - cz;
    float d = dx * dx + dy * dy + dz * dz;        // no fp contraction
    dbits = __float_as_uint(d);
}

// ===========================================================================
// Tier A (packed tables): {seg,bufidx} as uint2, {neural,ts} as float4.
// ===========================================================================

// Streams bufidx into the packed hash table (d-field = UINT_MAX) and packs
// neural+ts into 16B entries. Replaces the memset.
__global__ __launch_bounds__(256) void prep_packed(
    const int* __restrict__ bufidx,
    const float* __restrict__ neural,
    const int* __restrict__ ts_upd,
    uint2* __restrict__ p8,
    float4* __restrict__ pnt,
    int M)
{
    int j = blockIdx.x * 256 + threadIdx.x;
    if (j < BUFSZ)
        p8[j] = make_uint2(0xFFFFFFFFu, (unsigned)bufidx[j]);
    if (j < M)
        pnt[j] = make_float4(neural[3 * j + 0], neural[3 * j + 1],
                             neural[3 * j + 2], __int_as_float(ts_upd[j]));
}

__global__ __launch_bounds__(256) void pass_min_A(
    const float* __restrict__ points,
    unsigned int* __restrict__ p8w,     // viewing uint2 table as uint[2*BUFSZ]
    int N)
{
    int i = blockIdx.x * 256 + threadIdx.x;
    if (i >= N) return;
    float px = points[3 * i + 0];
    float py = points[3 * i + 1];
    float pz = points[3 * i + 2];
    int hw; unsigned dbits;
    voxel_hash_d(px, py, pz, hw, dbits);
    atomicMin(p8w + 2 * (long long)hw, dbits);
}

__global__ __launch_bounds__(256) void pass_out_A(
    const float* __restrict__ points,
    const uint2* __restrict__ p8,
    const float4* __restrict__ pnt,
    const float* __restrict__ travel,
    const int* __restrict__ cur_ts_p,
    float* __restrict__ out,
    int N, int M)
{
#pragma clang fp contract(off)
    int i = blockIdx.x * 256 + threadIdx.x;
    if (i >= N) return;

    float px = points[3 * i + 0];
    float py = points[3 * i + 1];
    float pz = points[3 * i + 2];
    int hw; unsigned dbits;
    voxel_hash_d(px, py, pz, hw, dbits);

    uint2 e = p8[hw];                              // one 8B gather: {min_d, bufidx}
    bool keep = dbits <= e.x;
    int hidx = (int)e.y;                           // -1 == empty slot
    int idxw = (hidx < 0) ? (hidx + M) : hidx;     // negative wrap -> M-1

    float4 nt = pnt[idxw];                         // one 16B gather: {x,y,z,ts}
    float vx = nt.x - px;
    float vy = nt.y - py;
    float vz = nt.z - pz;
    float dist2 = vx * vx + vy * vy + vz * vz;     // no contraction

    int ts = __float_as_int(nt.w);
    float dtv = travel[cur_ts_p[0]] - travel[ts];

    const float THR = (float)(3.0 * 0.3 * 0.3);
    bool upd = keep && ((hidx == -1) || (dist2 > THR) || (dtv > 120.0f));

    out[i]         = dist2;
    out[N + i]     = dtv;
    out[2 * N + i] = upd ? 1.0f : 0.0f;
}

// ===========================================================================
// Tier C (fallback, proven in R3): seg-only table, separate gathers.
// ===========================================================================

__global__ __launch_bounds__(256) void pass_min_C(
    const float* __restrict__ points,
    unsigned int* __restrict__ seg,
    int N)
{
    int i = blockIdx.x * 256 + threadIdx.x;
    if (i >= N) return;
    float px = points[3 * i + 0];
    float py = points[3 * i + 1];
    float pz = points[3 * i + 2];
    int hw; unsigned dbits;
    voxel_hash_d(px, py, pz, hw, dbits);
    atomicMin(seg + hw, dbits);
}

__global__ __launch_bounds__(256) void pass_out_C(
    const float* __restrict__ points,
    const float* __restrict__ neural,
    const int* __restrict__ bufidx,
    const float* __restrict__ travel,
    const int* __restrict__ ts_upd,
    const int* __restrict__ cur_ts_p,
    const unsigned int* __restrict__ seg,
    float* __restrict__ out,
    int N, int M)
{
#pragma clang fp contract(off)
    int i = blockIdx.x * 256 + threadIdx.x;
    if (i >= N) return;

    float px = points[3 * i + 0];
    float py = points[3 * i + 1];
    float pz = points[3 * i + 2];
    int hw; unsigned dbits;
    voxel_hash_d(px, py, pz, hw, dbits);

    bool keep = dbits <= seg[hw];
    int hidx = bufidx[hw];
    int idxw = (hidx < 0) ? (hidx + M) : hidx;

    float vx = neural[3 * idxw + 0] - px;
    float vy = neural[3 * idxw + 1] - py;
    float vz = neural[3 * idxw + 2] - pz;
    float dist2 = vx * vx + vy * vy + vz * vz;

    int ts = ts_upd[idxw];
    float dtv = travel[cur_ts_p[0]] - travel[ts];

    const float THR = (float)(3.0 * 0.3 * 0.3);
    bool upd = keep && ((hidx == -1) || (dist2 > THR) || (dtv > 120.0f));

    out[i]         = dist2;
    out[N + i]     = dtv;
    out[2 * N + i] = upd ? 1.0f : 0.0f;
}

extern "C" void kernel_launch(void* const* d_in, const int* in_sizes, int n_in,
                              void* d_out, int out_size, void* d_ws, size_t ws_size,
                              hipStream_t stream)
{
    const float* points  = (const float*)d_in[0];
    const float* neural  = (const float*)d_in[1];
    const int*   bufidx  = (const int*)d_in[2];
    const float* travel  = (const float*)d_in[3];
    const int*   ts_upd  = (const int*)d_in[4];
    const int*   cur_ts  = (const int*)d_in[5];

    int N = in_sizes[0] / 3;
    int M = in_sizes[1] / 3;

    int pblocks = (N + 255) / 256;

    const size_t needA = (size_t)BUFSZ * 8 + (size_t)M * 16;  // 112 MB
    if (ws_size >= needA) {
        uint2*  p8  = (uint2*)d_ws;                            // 80 MB
        float4* pnt = (float4*)((char*)d_ws + (size_t)BUFSZ * 8);  // 32 MB

        int jblocks = (BUFSZ + 255) / 256;
        prep_packed<<<jblocks, 256, 0, stream>>>(bufidx, neural, ts_upd, p8, pnt, M);
        pass_min_A<<<pblocks, 256, 0, stream>>>(points, (unsigned int*)p8, N);
        pass_out_A<<<pblocks, 256, 0, stream>>>(points, p8, pnt, travel, cur_ts,
                                                (float*)d_out, N, M);
    } else {
        unsigned int* seg = (unsigned int*)d_ws;               // 40 MB
        hipMemsetAsync(seg, 0xFF, (size_t)BUFSZ * sizeof(unsigned int), stream);
        pass_min_C<<<pblocks, 256, 0, stream>>>(points, seg, N);
        pass_out_C<<<pblocks, 256, 0, stream>>>(points, neural, bufidx, travel,
                                                ts_upd, cur_ts, seg,
                                                (float*)d_out, N, M);
    }
}